// Round 2
// baseline (1963.215 us; speedup 1.0000x reference)
//
#include <hip/hip_runtime.h>
#include <hip/hip_bf16.h>
#include <stdint.h>

#define T_STEPS 256
#define BATCH   64
#define IN_DIM  512
#define HID     1024
#define OUT_DIM 256
#define G4      4096
#define SENT32  0x7FC07FC0u
#define SENT64  0x7FC07FC07FC07FC0ULL

__device__ __forceinline__ float bfbits2f(uint32_t b16) {
    return __uint_as_float(b16 << 16);
}
__device__ __forceinline__ uint32_t f2bfbits(float f) {
    uint32_t u = __float_as_uint(f);
    u += 0x7fffu + ((u >> 16) & 1u);   // RNE; finite inputs, never produces 0x7FC0
    return u >> 16;
}
__device__ __forceinline__ float fast_sigmoid(float x) {
    return 1.f / (1.f + __expf(-x));
}
__device__ __forceinline__ float fast_tanh(float x) {
    return 2.f / (1.f + __expf(-2.f * x)) - 1.f;
}
// nonzero iff any 16-bit field of v equals the sentinel
__device__ __forceinline__ bool any_sent(uint64_t v) {
    uint64_t x = v ^ SENT64;
    return (((x - 0x0001000100010001ULL) & ~x) & 0x8000800080008000ULL) != 0ULL;
}
__device__ __forceinline__ uint64_t poll_load(const uint64_t* p) {
    return __hip_atomic_load(p, __ATOMIC_RELAXED, __HIP_MEMORY_SCOPE_AGENT);
}

// ---------------------------------------------------------------- init
__global__ void init_sent(uint32_t* __restrict__ p, int n) {
    int i = blockIdx.x * 256 + threadIdx.x;
    if (i < n) p[i] = SENT32;
}

// ---------------------------------------------------------------- GEMM C[M][N] = A[M][K]*B[N][K]^T + bias (fc only)
template<bool ABF16>
__global__ __launch_bounds__(256) void gemm_bt(
    const void* __restrict__ Av, long lda,
    const float* __restrict__ Bw, int ldb,
    const float* __restrict__ bias1,
    float* __restrict__ C, int ldc, int K)
{
    __shared__ float a_lds[64][68];
    __shared__ float w_lds[64][65];
    const int tid = threadIdx.x;
    const int m0 = blockIdx.y * 64, n0 = blockIdx.x * 64;
    const int kl = tid & 63, grp = tid >> 6;
    const int cc = tid & 31, r0 = (tid >> 5) * 8;

    float acc[16];
#pragma unroll
    for (int i = 0; i < 16; ++i) acc[i] = 0.f;

    for (int k0 = 0; k0 < K; k0 += 64) {
        __syncthreads();
#pragma unroll
        for (int i = 0; i < 16; ++i) {
            int r = grp + 4 * i;
            long ai = (long)(m0 + r) * lda + k0 + kl;
            float av = ABF16 ? bfbits2f(((const uint16_t*)Av)[ai])
                             : ((const float*)Av)[ai];
            a_lds[kl][r] = av;
            w_lds[kl][r] = Bw[(long)(n0 + r) * ldb + k0 + kl];
        }
        __syncthreads();
#pragma unroll 16
        for (int k = 0; k < 64; ++k) {
            float4 A0 = *(const float4*)&a_lds[k][r0];
            float4 A1 = *(const float4*)&a_lds[k][r0 + 4];
            float w0 = w_lds[k][cc], w1 = w_lds[k][cc + 32];
            float a[8] = {A0.x, A0.y, A0.z, A0.w, A1.x, A1.y, A1.z, A1.w};
#pragma unroll
            for (int i = 0; i < 8; ++i) {
                acc[i]     += a[i] * w0;
                acc[8 + i] += a[i] * w1;
            }
        }
    }
    float b0 = bias1[n0 + cc], b1 = bias1[n0 + cc + 32];
#pragma unroll
    for (int i = 0; i < 8; ++i) {
        C[(long)(m0 + r0 + i) * ldc + n0 + cc]      = acc[i]     + b0;
        C[(long)(m0 + r0 + i) * ldc + n0 + cc + 32] = acc[8 + i] + b1;
    }
}

// ---------------------------------------------------------------- fused xz + LSTM recurrence (batch 63)
// 256 blocks x 256 threads. Block g owns hidden units [4g,4g+4).
// row = tid>>4 = ju*4+gate  (ju = unit-in-block = wave index), kpart = tid&15.
// Prologue: xz[row][t] = x[t,63,:]·W_ih[grow,:] + b_ih + b_hh into LDS.
// Loop: poll h_{t-1} (1 uint64/thread, pipelined), LDS-stage, 1 barrier,
// 64 reg-MACs, intra-wave reduce+gather, gates on lane 0/wave, publish via
// global_store_short sc0 sc1 (data-as-flag, per-ushort NaN sentinel).
__global__ __launch_bounds__(256) void lstm_rec(
    const float* __restrict__ W_hh,   // [4096][1024]
    const float* __restrict__ x,      // [256][64][512]
    const float* __restrict__ W_ih,   // [4096][512]
    const float* __restrict__ b_ih,
    const float* __restrict__ b_hh,
    uint16_t* __restrict__ h_all)     // [256][1024] bf16 bits
{
    __shared__ float h_lds[2][HID];
    __shared__ float xz_lds[16][T_STEPS + 1];

    const int g     = blockIdx.x;
    const int tid   = threadIdx.x;
    const int kpart = tid & 15;
    const int row   = tid >> 4;        // 0..15
    const int ju    = row >> 2;        // unit-in-block == wave index
    const int gate  = row & 3;         // 0:i 1:f 2:g 3:o
    const int lane  = tid & 63;
    const int grow  = gate * HID + g * 4 + ju;

    // ---------------- prologue: xz rows for this block
    {
        float wih[32];
        const float* wp = W_ih + (long)grow * IN_DIM + kpart * 32;
#pragma unroll
        for (int i = 0; i < 8; ++i) {
            float4 v = *(const float4*)(wp + 4 * i);
            wih[4*i] = v.x; wih[4*i+1] = v.y; wih[4*i+2] = v.z; wih[4*i+3] = v.w;
        }
        float bsum = b_ih[grow] + b_hh[grow];
        const float* xbase = x + (long)63 * IN_DIM + (long)kpart * 32;
#pragma unroll 2
        for (int t = 0; t < T_STEPS; ++t) {
            const float* xp = xbase + (long)t * BATCH * IN_DIM;
            float a0 = 0.f, a1 = 0.f, a2 = 0.f, a3 = 0.f;
#pragma unroll
            for (int i = 0; i < 8; ++i) {
                float4 v = *(const float4*)(xp + 4 * i);
                a0 += v.x * wih[4*i];   a1 += v.y * wih[4*i+1];
                a2 += v.z * wih[4*i+2]; a3 += v.w * wih[4*i+3];
            }
            float acc = (a0 + a1) + (a2 + a3);
            acc += __shfl_xor(acc, 1, 16);
            acc += __shfl_xor(acc, 2, 16);
            acc += __shfl_xor(acc, 4, 16);
            acc += __shfl_xor(acc, 8, 16);
            if (kpart == 0) xz_lds[row][t] = acc + bsum;
        }
    }

    // ---------------- W_hh slice into registers (rotated chunk order)
    float w[64];
#pragma unroll
    for (int i = 0; i < 16; ++i) {
        int ch = (i + kpart) & 15;
        float4 wv = *(const float4*)&W_hh[(long)grow * HID + kpart * 64 + ch * 4];
        w[4*i] = wv.x; w[4*i+1] = wv.y; w[4*i+2] = wv.z; w[4*i+3] = wv.w;
    }

    // zero h_0 in buffer 0
    {
        float4 z4 = {0.f, 0.f, 0.f, 0.f};
        *(float4*)&h_lds[0][4 * tid] = z4;
    }
    __syncthreads();   // xz_lds + h_lds[0] ready

    float c_state = 0.f;               // live in lane 0 of each wave (unit ju)
    float xz_next = xz_lds[row][0];

    for (int t = 0; t < T_STEPS; ++t) {
        float* hb = h_lds[t & 1];
        if (t > 0) {
            const uint64_t* hsrc = (const uint64_t*)(h_all + (size_t)(t - 1) * HID);
            uint64_t v = poll_load(&hsrc[tid]);
            if (any_sent(v)) {
                // rotating 3-deep pipelined poll: check oldest, keep 2 in flight
                uint64_t a = poll_load(&hsrc[tid]);
                uint64_t b = poll_load(&hsrc[tid]);
                for (;;) {
                    v = a; a = b; b = poll_load(&hsrc[tid]);
                    if (!any_sent(v)) break;
                }
            }
            float4 hv = { bfbits2f((uint32_t)(v        & 0xFFFFu)),
                          bfbits2f((uint32_t)((v >> 16) & 0xFFFFu)),
                          bfbits2f((uint32_t)((v >> 32) & 0xFFFFu)),
                          bfbits2f((uint32_t)((v >> 48) & 0xFFFFu)) };
            *(float4*)&hb[4 * tid] = hv;
        }
        __syncthreads();   // single barrier per step (double-buffered h_lds)

        float xz_cur = xz_next;
        int tn = (t + 1 < T_STEPS) ? t + 1 : t;
        xz_next = xz_lds[row][tn];     // LDS broadcast prefetch, hidden under MAC

        float a0 = 0.f, a1 = 0.f, a2 = 0.f, a3 = 0.f;
#pragma unroll
        for (int i = 0; i < 16; ++i) {
            float4 hv = *(const float4*)&hb[kpart * 64 + ((i + kpart) & 15) * 4];
            a0 += w[4*i]   * hv.x;
            a1 += w[4*i+1] * hv.y;
            a2 += w[4*i+2] * hv.z;
            a3 += w[4*i+3] * hv.w;
        }
        float sum = (a0 + a1) + (a2 + a3);
        sum += __shfl_xor(sum, 1, 16);
        sum += __shfl_xor(sum, 2, 16);
        sum += __shfl_xor(sum, 4, 16);
        sum += __shfl_xor(sum, 8, 16);
        float z = sum + xz_cur;        // all lanes of the 16-group hold z[row]

        // gather this wave's unit gates: rows ju*4+{0,1,2,3} = lane groups 0/16/32/48
        float zi = __shfl(z,  0, 64);
        float zf = __shfl(z, 16, 64);
        float zg = __shfl(z, 32, 64);
        float zo = __shfl(z, 48, 64);
        if (lane == 0) {
            float ii = fast_sigmoid(zi);
            float ff = fast_sigmoid(zf);
            float gg = fast_tanh(zg);
            float oo = fast_sigmoid(zo);
            c_state = ff * c_state + ii * gg;
            float h = oo * fast_tanh(c_state);
            uint32_t hv32 = f2bfbits(h);
            uint16_t* dst = h_all + (size_t)t * HID + g * 4 + ju;
            asm volatile("global_store_short %0, %1, off sc0 sc1"
                         :: "v"(dst), "v"(hv32) : "memory");
        }
    }
}

// ---------------------------------------------------------------- launch
extern "C" void kernel_launch(void* const* d_in, const int* in_sizes, int n_in,
                              void* d_out, int out_size, void* d_ws, size_t ws_size,
                              hipStream_t stream) {
    const float* x    = (const float*)d_in[0];
    const float* W_ih = (const float*)d_in[1];
    const float* W_hh = (const float*)d_in[2];
    const float* b_ih = (const float*)d_in[3];
    const float* b_hh = (const float*)d_in[4];
    const float* fc_W = (const float*)d_in[5];
    const float* fc_b = (const float*)d_in[6];
    float* out = (float*)d_out;

    uint16_t* h_all = (uint16_t*)d_ws;   // [256][1024] bf16 bits = 512 KB

    // re-sentinel every replay (graph-captured)
    init_sent<<<(T_STEPS * HID / 2 + 255) / 256, 256, 0, stream>>>(
        (uint32_t*)h_all, T_STEPS * HID / 2);

    // fused xz-GEMM + sequential recurrence
    lstm_rec<<<256, 256, 0, stream>>>(W_hh, x, W_ih, b_ih, b_hh, h_all);

    // out[t][o] = h_all[t][:]·fc_W[o][:] + fc_b[o]
    gemm_bt<true><<<dim3(OUT_DIM / 64, T_STEPS / 64), 256, 0, stream>>>(
        (const void*)h_all, HID, fc_W, HID, fc_b, out, OUT_DIM, HID);
}

// Round 3
// 1232.462 us; speedup vs baseline: 1.5929x; 1.5929x over previous
//
#include <hip/hip_runtime.h>
#include <hip/hip_bf16.h>
#include <stdint.h>

#define T_STEPS 256
#define BATCH   64
#define IN_DIM  512
#define HID     1024
#define OUT_DIM 256
#define G4      4096
#define SENT32  0x7FC07FC0u
#define SENT64  0x7FC07FC07FC07FC0ULL

__device__ __forceinline__ float bfbits2f(uint32_t b16) {
    return __uint_as_float(b16 << 16);
}
__device__ __forceinline__ uint32_t f2bfbits(float f) {
    uint32_t u = __float_as_uint(f);
    u += 0x7fffu + ((u >> 16) & 1u);   // RNE; finite inputs, never 0x7FC0
    return u >> 16;
}
__device__ __forceinline__ float fast_sigmoid(float x) {
    return 1.f / (1.f + __expf(-x));
}
__device__ __forceinline__ float fast_tanh(float x) {
    return 2.f / (1.f + __expf(-2.f * x)) - 1.f;
}
// nonzero iff any 16-bit field of v equals the sentinel
__device__ __forceinline__ bool any_sent(uint64_t v) {
    uint64_t x = v ^ SENT64;
    return (((x - 0x0001000100010001ULL) & ~x) & 0x8000800080008000ULL) != 0ULL;
}
__device__ __forceinline__ uint64_t poll_load(const uint64_t* p) {
    return __hip_atomic_load(p, __ATOMIC_RELAXED, __HIP_MEMORY_SCOPE_AGENT);
}

// ---------------------------------------------------------------- init
__global__ void init_sent(uint32_t* __restrict__ p, int n) {
    int i = blockIdx.x * 256 + threadIdx.x;
    if (i < n) p[i] = SENT32;
}

// ---------------------------------------------------------------- GEMM C[M][N] = A[M][K]*B[N][K]^T + bias (fc only)
template<bool ABF16>
__global__ __launch_bounds__(256) void gemm_bt(
    const void* __restrict__ Av, long lda,
    const float* __restrict__ Bw, int ldb,
    const float* __restrict__ bias1,
    float* __restrict__ C, int ldc, int K)
{
    __shared__ float a_lds[64][68];
    __shared__ float w_lds[64][65];
    const int tid = threadIdx.x;
    const int m0 = blockIdx.y * 64, n0 = blockIdx.x * 64;
    const int kl = tid & 63, grp = tid >> 6;
    const int cc = tid & 31, r0 = (tid >> 5) * 8;

    float acc[16];
#pragma unroll
    for (int i = 0; i < 16; ++i) acc[i] = 0.f;

    for (int k0 = 0; k0 < K; k0 += 64) {
        __syncthreads();
#pragma unroll
        for (int i = 0; i < 16; ++i) {
            int r = grp + 4 * i;
            long ai = (long)(m0 + r) * lda + k0 + kl;
            float av = ABF16 ? bfbits2f(((const uint16_t*)Av)[ai])
                             : ((const float*)Av)[ai];
            a_lds[kl][r] = av;
            w_lds[kl][r] = Bw[(long)(n0 + r) * ldb + k0 + kl];
        }
        __syncthreads();
#pragma unroll 16
        for (int k = 0; k < 64; ++k) {
            float4 A0 = *(const float4*)&a_lds[k][r0];
            float4 A1 = *(const float4*)&a_lds[k][r0 + 4];
            float w0 = w_lds[k][cc], w1 = w_lds[k][cc + 32];
            float a[8] = {A0.x, A0.y, A0.z, A0.w, A1.x, A1.y, A1.z, A1.w};
#pragma unroll
            for (int i = 0; i < 8; ++i) {
                acc[i]     += a[i] * w0;
                acc[8 + i] += a[i] * w1;
            }
        }
    }
    float b0 = bias1[n0 + cc], b1 = bias1[n0 + cc + 32];
#pragma unroll
    for (int i = 0; i < 8; ++i) {
        C[(long)(m0 + r0 + i) * ldc + n0 + cc]      = acc[i]     + b0;
        C[(long)(m0 + r0 + i) * ldc + n0 + cc + 32] = acc[8 + i] + b1;
    }
}

// ---------------------------------------------------------------- fused xz + LSTM recurrence (batch 63)
// 256 blocks x 256 threads, launch_bounds(256,1) so w[64] stays in VGPRs.
// Block g owns hidden units [4g,4g+4). row = tid>>4, gate = row>>2, ju = row&3.
// Per step: poll ONE uint64 per thread (single 8B producer store per block ->
// all-or-nothing detection), stage to LDS, barrier, 64 reg-MACs, 16-lane
// reduce, z_lds, barrier, gates on threads 0..3, pack 4xbf16, ONE 8B store.
__global__ __launch_bounds__(256, 1) void lstm_rec(
    const float* __restrict__ W_hh,   // [4096][1024]
    const float* __restrict__ x,      // [256][64][512]
    const float* __restrict__ W_ih,   // [4096][512]
    const float* __restrict__ b_ih,
    const float* __restrict__ b_hh,
    uint64_t* __restrict__ h_all)     // [256][256] uint64 (= [256][1024] bf16)
{
    __shared__ float h_lds[2][HID];
    __shared__ float xz_lds[16][T_STEPS + 1];
    __shared__ float z_lds[16];

    const int g     = blockIdx.x;
    const int tid   = threadIdx.x;
    const int kpart = tid & 15;
    const int row   = tid >> 4;        // 0..15
    const int gate  = row >> 2;        // 0:i 1:f 2:g 3:o
    const int ju    = row & 3;         // unit-in-block
    const int grow  = gate * HID + g * 4 + ju;

    // ---------------- prologue: xz rows for this block (into LDS)
    {
        float wih[32];
        const float* wp = W_ih + (long)grow * IN_DIM + kpart * 32;
#pragma unroll
        for (int i = 0; i < 8; ++i) {
            float4 v = *(const float4*)(wp + 4 * i);
            wih[4*i] = v.x; wih[4*i+1] = v.y; wih[4*i+2] = v.z; wih[4*i+3] = v.w;
        }
        float bsum = b_ih[grow] + b_hh[grow];
        const float* xbase = x + (long)63 * IN_DIM + (long)kpart * 32;
#pragma unroll 2
        for (int t = 0; t < T_STEPS; ++t) {
            const float* xp = xbase + (long)t * BATCH * IN_DIM;
            float a0 = 0.f, a1 = 0.f, a2 = 0.f, a3 = 0.f;
#pragma unroll
            for (int i = 0; i < 8; ++i) {
                float4 v = *(const float4*)(xp + 4 * i);
                a0 += v.x * wih[4*i];   a1 += v.y * wih[4*i+1];
                a2 += v.z * wih[4*i+2]; a3 += v.w * wih[4*i+3];
            }
            float acc = (a0 + a1) + (a2 + a3);
            acc += __shfl_xor(acc, 1, 16);
            acc += __shfl_xor(acc, 2, 16);
            acc += __shfl_xor(acc, 4, 16);
            acc += __shfl_xor(acc, 8, 16);
            if (kpart == 0) xz_lds[row][t] = acc + bsum;
        }
    }

    // ---------------- W_hh slice into registers (rotated chunk order)
    float w[64];
#pragma unroll
    for (int i = 0; i < 16; ++i) {
        int ch = (i + kpart) & 15;
        float4 wv = *(const float4*)&W_hh[(long)grow * HID + kpart * 64 + ch * 4];
        w[4*i] = wv.x; w[4*i+1] = wv.y; w[4*i+2] = wv.z; w[4*i+3] = wv.w;
    }

    // zero h_0 in buffer 0
    {
        float4 z4 = {0.f, 0.f, 0.f, 0.f};
        *(float4*)&h_lds[0][4 * tid] = z4;
    }
    __syncthreads();   // xz_lds + h_lds[0] ready

    float c_state = 0.f;               // live in threads 0..3 (unit = tid)
    float xz_next = xz_lds[row][0];

    for (int t = 0; t < T_STEPS; ++t) {
        float* hb = h_lds[t & 1];
        if (t > 0) {
            const uint64_t* hsrc = h_all + (size_t)(t - 1) * 256;
            uint64_t v = poll_load(&hsrc[tid]);
            if (any_sent(v)) {
                // rotating 3-deep pipelined poll: check oldest, keep 2 in flight
                uint64_t a = poll_load(&hsrc[tid]);
                uint64_t b = poll_load(&hsrc[tid]);
                for (;;) {
                    v = a; a = b; b = poll_load(&hsrc[tid]);
                    if (!any_sent(v)) break;
                }
            }
            float4 hv = { bfbits2f((uint32_t)( v        & 0xFFFFu)),
                          bfbits2f((uint32_t)((v >> 16) & 0xFFFFu)),
                          bfbits2f((uint32_t)((v >> 32) & 0xFFFFu)),
                          bfbits2f((uint32_t)((v >> 48) & 0xFFFFu)) };
            *(float4*)&hb[4 * tid] = hv;
        }
        __syncthreads();   // A: h ready

        float xz_cur = xz_next;
        int tn = (t + 1 < T_STEPS) ? t + 1 : t;
        xz_next = xz_lds[row][tn];     // LDS prefetch, hidden under MAC

        float a0 = 0.f, a1 = 0.f, a2 = 0.f, a3 = 0.f;
#pragma unroll
        for (int i = 0; i < 16; ++i) {
            float4 hv = *(const float4*)&hb[kpart * 64 + ((i + kpart) & 15) * 4];
            a0 += w[4*i]   * hv.x;
            a1 += w[4*i+1] * hv.y;
            a2 += w[4*i+2] * hv.z;
            a3 += w[4*i+3] * hv.w;
        }
        float sum = (a0 + a1) + (a2 + a3);
        sum += __shfl_xor(sum, 1, 16);
        sum += __shfl_xor(sum, 2, 16);
        sum += __shfl_xor(sum, 4, 16);
        sum += __shfl_xor(sum, 8, 16);
        if (kpart == 0) z_lds[row] = sum + xz_cur;
        __syncthreads();   // B: z ready; h_lds reads done

        // gates + state update + single packed publish (threads 0..3, wave 0)
        if (tid < 4) {
            float zi = z_lds[tid], zf = z_lds[4 + tid];
            float zg = z_lds[8 + tid], zo = z_lds[12 + tid];
            float ii = fast_sigmoid(zi);
            float ff = fast_sigmoid(zf);
            float gg = fast_tanh(zg);
            float oo = fast_sigmoid(zo);
            c_state = ff * c_state + ii * gg;
            float h = oo * fast_tanh(c_state);
            uint32_t hb16 = f2bfbits(h);
            uint32_t b1 = __shfl(hb16, 1, 64);
            uint32_t b2 = __shfl(hb16, 2, 64);
            uint32_t b3 = __shfl(hb16, 3, 64);
            if (tid == 0) {
                uint64_t dw = (uint64_t)(hb16 | (b1 << 16))
                            | ((uint64_t)(b2 | (b3 << 16)) << 32);
                __hip_atomic_store(&h_all[(size_t)t * 256 + g], dw,
                                   __ATOMIC_RELAXED, __HIP_MEMORY_SCOPE_AGENT);
            }
        }
    }
}

// ---------------------------------------------------------------- launch
extern "C" void kernel_launch(void* const* d_in, const int* in_sizes, int n_in,
                              void* d_out, int out_size, void* d_ws, size_t ws_size,
                              hipStream_t stream) {
    const float* x    = (const float*)d_in[0];
    const float* W_ih = (const float*)d_in[1];
    const float* W_hh = (const float*)d_in[2];
    const float* b_ih = (const float*)d_in[3];
    const float* b_hh = (const float*)d_in[4];
    const float* fc_W = (const float*)d_in[5];
    const float* fc_b = (const float*)d_in[6];
    float* out = (float*)d_out;

    uint64_t* h_all = (uint64_t*)d_ws;   // [256][256] uint64 = 512 KB

    // re-sentinel every replay (graph-captured)
    init_sent<<<(T_STEPS * HID / 2 + 255) / 256, 256, 0, stream>>>(
        (uint32_t*)h_all, T_STEPS * HID / 2);

    // fused xz-GEMM + sequential recurrence
    lstm_rec<<<256, 256, 0, stream>>>(W_hh, x, W_ih, b_ih, b_hh, h_all);

    // out[t][o] = h_all[t][:]·fc_W[o][:] + fc_b[o]
    gemm_bt<true><<<dim3(OUT_DIM / 64, T_STEPS / 64), 256, 0, stream>>>(
        (const void*)h_all, HID, fc_W, HID, fc_b, out, OUT_DIM, HID);
}

// Round 4
// 1142.301 us; speedup vs baseline: 1.7186x; 1.0789x over previous
//
#include <hip/hip_runtime.h>
#include <hip/hip_bf16.h>
#include <stdint.h>

#define T_STEPS 256
#define BATCH   64
#define IN_DIM  512
#define HID     1024
#define OUT_DIM 256
#define G4      4096
#define SENT32  0x7FC07FC0u
#define SENT64  0x7FC07FC07FC07FC0ULL

__device__ __forceinline__ float bfbits2f(uint32_t b16) {
    return __uint_as_float(b16 << 16);
}
__device__ __forceinline__ uint32_t f2bfbits(float f) {
    uint32_t u = __float_as_uint(f);
    u += 0x7fffu + ((u >> 16) & 1u);   // RNE; finite inputs, never 0x7FC0
    return u >> 16;
}
__device__ __forceinline__ float fast_sigmoid(float x) {
    return 1.f / (1.f + __expf(-x));
}
__device__ __forceinline__ float fast_tanh(float x) {
    return 2.f / (1.f + __expf(-2.f * x)) - 1.f;
}
// nonzero iff any 16-bit field equals the sentinel (exact for our use:
// false positives only occur together with a true positive)
__device__ __forceinline__ bool any_sent(uint64_t v) {
    uint64_t x = v ^ SENT64;
    return (((x - 0x0001000100010001ULL) & ~x) & 0x8000800080008000ULL) != 0ULL;
}
__device__ __forceinline__ uint64_t poll_load(const uint64_t* p) {
    return __hip_atomic_load(p, __ATOMIC_RELAXED, __HIP_MEMORY_SCOPE_AGENT);
}

// ---------------------------------------------------------------- init
__global__ void init_sent(uint32_t* __restrict__ p, int n) {
    int i = blockIdx.x * 256 + threadIdx.x;
    if (i < n) p[i] = SENT32;
}

// ---------------------------------------------------------------- GEMM C[M][N] = A[M][K]*B[N][K]^T + bias (fc only)
template<bool ABF16>
__global__ __launch_bounds__(256) void gemm_bt(
    const void* __restrict__ Av, long lda,
    const float* __restrict__ Bw, int ldb,
    const float* __restrict__ bias1,
    float* __restrict__ C, int ldc, int K)
{
    __shared__ float a_lds[64][68];
    __shared__ float w_lds[64][65];
    const int tid = threadIdx.x;
    const int m0 = blockIdx.y * 64, n0 = blockIdx.x * 64;
    const int kl = tid & 63, grp = tid >> 6;
    const int cc = tid & 31, r0 = (tid >> 5) * 8;

    float acc[16];
#pragma unroll
    for (int i = 0; i < 16; ++i) acc[i] = 0.f;

    for (int k0 = 0; k0 < K; k0 += 64) {
        __syncthreads();
#pragma unroll
        for (int i = 0; i < 16; ++i) {
            int r = grp + 4 * i;
            long ai = (long)(m0 + r) * lda + k0 + kl;
            float av = ABF16 ? bfbits2f(((const uint16_t*)Av)[ai])
                             : ((const float*)Av)[ai];
            a_lds[kl][r] = av;
            w_lds[kl][r] = Bw[(long)(n0 + r) * ldb + k0 + kl];
        }
        __syncthreads();
#pragma unroll 16
        for (int k = 0; k < 64; ++k) {
            float4 A0 = *(const float4*)&a_lds[k][r0];
            float4 A1 = *(const float4*)&a_lds[k][r0 + 4];
            float w0 = w_lds[k][cc], w1 = w_lds[k][cc + 32];
            float a[8] = {A0.x, A0.y, A0.z, A0.w, A1.x, A1.y, A1.z, A1.w};
#pragma unroll
            for (int i = 0; i < 8; ++i) {
                acc[i]     += a[i] * w0;
                acc[8 + i] += a[i] * w1;
            }
        }
    }
    float b0 = bias1[n0 + cc], b1 = bias1[n0 + cc + 32];
#pragma unroll
    for (int i = 0; i < 8; ++i) {
        C[(long)(m0 + r0 + i) * ldc + n0 + cc]      = acc[i]     + b0;
        C[(long)(m0 + r0 + i) * ldc + n0 + cc + 32] = acc[8 + i] + b1;
    }
}

// ---------------------------------------------------------------- fused xz + LSTM recurrence (batch 63)
// 128 blocks x 512 threads, 1 block/CU (LDS > 80 KB). Block g owns units
// [8g, 8g+8) -> 32 gate rows (row = gate*8 + ju). W_hh slice in 16 NAMED
// float4 registers per thread (64 VGPRs, cannot be demoted). Per step:
// 128 threads poll one 16B granule (2 u64, 3-deep pipelined), stage to LDS,
// barrier, 64 reg-MACs, 16-lane reduce, z_lds, barrier, gates on threads
// 0..7, pack 16 bf16 to thread 0, ONE 16B publish (2 u64 agent stores).
#define GROWX(RR) ((long)((RR) >> 3) * HID + 8 * g + ((RR) & 7))

#define WINIT(I) { const int ch_ = ((I) + kpart) & 15; \
    w##I = *(const float4*)(W_hh + wbase + ch_ * 4); }

#define MACS(I) { const float4 hv_ = *(const float4*)(hb + hoff + (((I) + kpart) & 15) * 4); \
    a0 = fmaf(w##I.x, hv_.x, a0); a1 = fmaf(w##I.y, hv_.y, a1); \
    a2 = fmaf(w##I.z, hv_.z, a2); a3 = fmaf(w##I.w, hv_.w, a3); }

__global__ __launch_bounds__(512, 2) void lstm_rec(
    const float* __restrict__ W_hh,   // [4096][1024]
    const float* __restrict__ x,      // [256][64][512]
    const float* __restrict__ W_ih,   // [4096][512]
    const float* __restrict__ b_ih,
    const float* __restrict__ b_hh,
    uint64_t* __restrict__ h_all)     // [256][256] u64 (= [256][1024] bf16)
{
    __shared__ float h_lds[2][HID];            //  8 KB
    __shared__ float xz_lds[32][T_STEPS + 1];  // 32.9 KB
    __shared__ float z_lds[32];
    extern __shared__ float dyn_pad[];         // +41 KB at launch -> 1 block/CU

    const int g   = blockIdx.x;   // 0..127
    const int tid = threadIdx.x;

    // ---------------- prologue: xz rows for this block (into LDS)
    {
        const int wv = tid >> 6;        // row-group: rows 4wv..4wv+3
        const int ln = tid & 63;        // k-part: x cols [8ln, 8ln+8)
        const int rr0 = 4 * wv;
        const long gr0 = GROWX(rr0), gr1 = GROWX(rr0 + 1),
                   gr2 = GROWX(rr0 + 2), gr3 = GROWX(rr0 + 3);
        const float4 p0a = *(const float4*)(W_ih + gr0 * IN_DIM + 8 * ln);
        const float4 p0b = *(const float4*)(W_ih + gr0 * IN_DIM + 8 * ln + 4);
        const float4 p1a = *(const float4*)(W_ih + gr1 * IN_DIM + 8 * ln);
        const float4 p1b = *(const float4*)(W_ih + gr1 * IN_DIM + 8 * ln + 4);
        const float4 p2a = *(const float4*)(W_ih + gr2 * IN_DIM + 8 * ln);
        const float4 p2b = *(const float4*)(W_ih + gr2 * IN_DIM + 8 * ln + 4);
        const float4 p3a = *(const float4*)(W_ih + gr3 * IN_DIM + 8 * ln);
        const float4 p3b = *(const float4*)(W_ih + gr3 * IN_DIM + 8 * ln + 4);
        const float bs0 = b_ih[gr0] + b_hh[gr0];
        const float bs1 = b_ih[gr1] + b_hh[gr1];
        const float bs2 = b_ih[gr2] + b_hh[gr2];
        const float bs3 = b_ih[gr3] + b_hh[gr3];
        for (int t = 0; t < T_STEPS; ++t) {
            const float* xp = x + ((long)t * BATCH + 63) * IN_DIM + 8 * ln;
            const float4 xa = *(const float4*)xp;
            const float4 xb = *(const float4*)(xp + 4);
            float s0 = xa.x*p0a.x + xa.y*p0a.y + xa.z*p0a.z + xa.w*p0a.w
                     + xb.x*p0b.x + xb.y*p0b.y + xb.z*p0b.z + xb.w*p0b.w;
            float s1 = xa.x*p1a.x + xa.y*p1a.y + xa.z*p1a.z + xa.w*p1a.w
                     + xb.x*p1b.x + xb.y*p1b.y + xb.z*p1b.z + xb.w*p1b.w;
            float s2 = xa.x*p2a.x + xa.y*p2a.y + xa.z*p2a.z + xa.w*p2a.w
                     + xb.x*p2b.x + xb.y*p2b.y + xb.z*p2b.z + xb.w*p2b.w;
            float s3 = xa.x*p3a.x + xa.y*p3a.y + xa.z*p3a.z + xa.w*p3a.w
                     + xb.x*p3b.x + xb.y*p3b.y + xb.z*p3b.z + xb.w*p3b.w;
#pragma unroll
            for (int d = 1; d < 64; d <<= 1) {
                s0 += __shfl_xor(s0, d, 64);
                s1 += __shfl_xor(s1, d, 64);
                s2 += __shfl_xor(s2, d, 64);
                s3 += __shfl_xor(s3, d, 64);
            }
            if (ln == 0) {
                xz_lds[rr0 + 0][t] = s0 + bs0;
                xz_lds[rr0 + 1][t] = s1 + bs1;
                xz_lds[rr0 + 2][t] = s2 + bs2;
                xz_lds[rr0 + 3][t] = s3 + bs3;
            }
        }
    }

    // zero h_0 into buffer 0
    if (tid < 256) {
        float4 z4 = {0.f, 0.f, 0.f, 0.f};
        *(float4*)&h_lds[0][4 * tid] = z4;
    }

    // ---------------- W_hh slice into 16 NAMED float4 registers
    const int kpart = tid & 15;
    const int row   = tid >> 4;          // 0..31: gate = row>>3, ju = row&7
    const long grow  = GROWX(row);
    const long wbase = grow * HID + kpart * 64;
    const int  hoff  = kpart * 64;
    float4 w0, w1, w2, w3, w4, w5, w6, w7, w8, w9, w10, w11, w12, w13, w14, w15;
    WINIT(0)  WINIT(1)  WINIT(2)  WINIT(3)
    WINIT(4)  WINIT(5)  WINIT(6)  WINIT(7)
    WINIT(8)  WINIT(9)  WINIT(10) WINIT(11)
    WINIT(12) WINIT(13) WINIT(14) WINIT(15)

    __syncthreads();   // xz_lds + h_lds[0] ready

    float c_state = 0.f;                 // used by threads 0..7 (unit = tid)
    float xz_next = xz_lds[row][0];

    for (int t = 0; t < T_STEPS; ++t) {
        float* hb = h_lds[t & 1];
        if (t > 0 && tid < 128) {
            const uint64_t* src = h_all + (size_t)(t - 1) * 256 + 2 * tid;
            uint64_t v0 = poll_load(src), v1 = poll_load(src + 1);
            if (any_sent(v0) | any_sent(v1)) {
                uint64_t a0_ = poll_load(src), a1_ = poll_load(src + 1);
                uint64_t b0_ = poll_load(src), b1_ = poll_load(src + 1);
                for (;;) {
                    uint64_t c0_ = poll_load(src), c1_ = poll_load(src + 1);
                    if (!(any_sent(v0) | any_sent(v1))) break;
                    v0 = a0_; v1 = a1_;
                    a0_ = b0_; a1_ = b1_;
                    b0_ = c0_; b1_ = c1_;
                }
            }
            float4 f0 = { bfbits2f((uint32_t)( v0        & 0xFFFFu)),
                          bfbits2f((uint32_t)((v0 >> 16) & 0xFFFFu)),
                          bfbits2f((uint32_t)((v0 >> 32) & 0xFFFFu)),
                          bfbits2f((uint32_t)((v0 >> 48) & 0xFFFFu)) };
            float4 f1 = { bfbits2f((uint32_t)( v1        & 0xFFFFu)),
                          bfbits2f((uint32_t)((v1 >> 16) & 0xFFFFu)),
                          bfbits2f((uint32_t)((v1 >> 32) & 0xFFFFu)),
                          bfbits2f((uint32_t)((v1 >> 48) & 0xFFFFu)) };
            *(float4*)&hb[8 * tid]     = f0;
            *(float4*)&hb[8 * tid + 4] = f1;
        }
        __syncthreads();   // A: h ready

        const float xz_cur = xz_next;
        const int tn = (t + 1 < T_STEPS) ? t + 1 : t;
        xz_next = xz_lds[row][tn];       // LDS broadcast prefetch

        float a0 = 0.f, a1 = 0.f, a2 = 0.f, a3 = 0.f;
        MACS(0)  MACS(1)  MACS(2)  MACS(3)
        MACS(4)  MACS(5)  MACS(6)  MACS(7)
        MACS(8)  MACS(9)  MACS(10) MACS(11)
        MACS(12) MACS(13) MACS(14) MACS(15)
        float sum = (a0 + a1) + (a2 + a3);
        sum += __shfl_xor(sum, 1, 16);
        sum += __shfl_xor(sum, 2, 16);
        sum += __shfl_xor(sum, 4, 16);
        sum += __shfl_xor(sum, 8, 16);
        if (kpart == 0) z_lds[row] = sum + xz_cur;
        __syncthreads();   // B: z ready; h_lds reads done

        // gates + state update + single 16B publish
        if (tid < 8) {
            const float zi = z_lds[tid],      zf = z_lds[8 + tid];
            const float zg = z_lds[16 + tid], zo = z_lds[24 + tid];
            const float ii = fast_sigmoid(zi);
            const float ff = fast_sigmoid(zf);
            const float gg = fast_tanh(zg);
            const float oo = fast_sigmoid(zo);
            c_state = ff * c_state + ii * gg;
            const float h = oo * fast_tanh(c_state);
            uint32_t hbv = f2bfbits(h);
            uint32_t lo  = hbv | (__shfl_down(hbv, 1, 64) << 16);  // even lanes
            uint64_t A = (uint64_t)lo | ((uint64_t)__shfl(lo, 2, 64) << 32);
            uint64_t B = (uint64_t)__shfl(lo, 4, 64)
                       | ((uint64_t)__shfl(lo, 6, 64) << 32);
            if (tid == 0) {
                uint64_t* dst = h_all + (size_t)t * 256 + 2 * g;
                __hip_atomic_store(dst,     A, __ATOMIC_RELAXED, __HIP_MEMORY_SCOPE_AGENT);
                __hip_atomic_store(dst + 1, B, __ATOMIC_RELAXED, __HIP_MEMORY_SCOPE_AGENT);
            }
        }
    }
    (void)dyn_pad;
}

// ---------------------------------------------------------------- launch
extern "C" void kernel_launch(void* const* d_in, const int* in_sizes, int n_in,
                              void* d_out, int out_size, void* d_ws, size_t ws_size,
                              hipStream_t stream) {
    const float* x    = (const float*)d_in[0];
    const float* W_ih = (const float*)d_in[1];
    const float* W_hh = (const float*)d_in[2];
    const float* b_ih = (const float*)d_in[3];
    const float* b_hh = (const float*)d_in[4];
    const float* fc_W = (const float*)d_in[5];
    const float* fc_b = (const float*)d_in[6];
    float* out = (float*)d_out;

    uint64_t* h_all = (uint64_t*)d_ws;   // [256][256] u64 = 512 KB

    // re-sentinel every replay (graph-captured)
    init_sent<<<512, 256, 0, stream>>>((uint32_t*)h_all, T_STEPS * HID / 2);

    // fused xz-GEMM + sequential recurrence; 41 KB dynamic LDS pads the
    // static 41 KB past 80 KB so exactly one block fits per CU.
    lstm_rec<<<128, 512, 41984, stream>>>(W_hh, x, W_ih, b_ih, b_hh, h_all);

    // out[t][o] = h_all[t][:]·fc_W[o][:] + fc_b[o]
    gemm_bt<true><<<dim3(OUT_DIM / 64, T_STEPS / 64), 256, 0, stream>>>(
        (const void*)h_all, HID, fc_W, HID, fc_b, out, OUT_DIM, HID);
}

// Round 5
// 1077.788 us; speedup vs baseline: 1.8215x; 1.0599x over previous
//
#include <hip/hip_runtime.h>
#include <hip/hip_bf16.h>
#include <stdint.h>

#define T_STEPS 256
#define BATCH   64
#define IN_DIM  512
#define HID     1024
#define OUT_DIM 256
#define G4      4096
#define SENT32  0x7FC07FC0u
#define SENT64  0x7FC07FC07FC07FC0ULL

__device__ __forceinline__ float bfbits2f(uint32_t b16) {
    return __uint_as_float(b16 << 16);
}
__device__ __forceinline__ uint32_t f2bfbits(float f) {
    uint32_t u = __float_as_uint(f);
    u += 0x7fffu + ((u >> 16) & 1u);   // RNE; finite inputs, never 0x7FC0
    return u >> 16;
}
__device__ __forceinline__ float fast_sigmoid(float x) {
    return 1.f / (1.f + __expf(-x));
}
__device__ __forceinline__ float fast_tanh(float x) {
    return 2.f / (1.f + __expf(-2.f * x)) - 1.f;
}
__device__ __forceinline__ bool any_sent(uint64_t v) {
    uint64_t x = v ^ SENT64;
    return (((x - 0x0001000100010001ULL) & ~x) & 0x8000800080008000ULL) != 0ULL;
}
__device__ __forceinline__ uint64_t poll_load(const uint64_t* p) {
    return __hip_atomic_load(p, __ATOMIC_RELAXED, __HIP_MEMORY_SCOPE_AGENT);
}

// ---------------------------------------------------------------- init
__global__ void init_sent(uint32_t* __restrict__ p, int n) {
    int i = blockIdx.x * 256 + threadIdx.x;
    if (i < n) p[i] = SENT32;
}

// ---------------------------------------------------------------- GEMM C[M][N] = A[M][K]*B[N][K]^T + bias (fc only)
template<bool ABF16>
__global__ __launch_bounds__(256) void gemm_bt(
    const void* __restrict__ Av, long lda,
    const float* __restrict__ Bw, int ldb,
    const float* __restrict__ bias1,
    float* __restrict__ C, int ldc, int K)
{
    __shared__ float a_lds[64][68];
    __shared__ float w_lds[64][65];
    const int tid = threadIdx.x;
    const int m0 = blockIdx.y * 64, n0 = blockIdx.x * 64;
    const int kl = tid & 63, grp = tid >> 6;
    const int cc = tid & 31, r0 = (tid >> 5) * 8;

    float acc[16];
#pragma unroll
    for (int i = 0; i < 16; ++i) acc[i] = 0.f;

    for (int k0 = 0; k0 < K; k0 += 64) {
        __syncthreads();
#pragma unroll
        for (int i = 0; i < 16; ++i) {
            int r = grp + 4 * i;
            long ai = (long)(m0 + r) * lda + k0 + kl;
            float av = ABF16 ? bfbits2f(((const uint16_t*)Av)[ai])
                             : ((const float*)Av)[ai];
            a_lds[kl][r] = av;
            w_lds[kl][r] = Bw[(long)(n0 + r) * ldb + k0 + kl];
        }
        __syncthreads();
#pragma unroll 16
        for (int k = 0; k < 64; ++k) {
            float4 A0 = *(const float4*)&a_lds[k][r0];
            float4 A1 = *(const float4*)&a_lds[k][r0 + 4];
            float w0 = w_lds[k][cc], w1 = w_lds[k][cc + 32];
            float a[8] = {A0.x, A0.y, A0.z, A0.w, A1.x, A1.y, A1.z, A1.w};
#pragma unroll
            for (int i = 0; i < 8; ++i) {
                acc[i]     += a[i] * w0;
                acc[8 + i] += a[i] * w1;
            }
        }
    }
    float b0 = bias1[n0 + cc], b1 = bias1[n0 + cc + 32];
#pragma unroll
    for (int i = 0; i < 8; ++i) {
        C[(long)(m0 + r0 + i) * ldc + n0 + cc]      = acc[i]     + b0;
        C[(long)(m0 + r0 + i) * ldc + n0 + cc + 32] = acc[8 + i] + b1;
    }
}

// ---------------------------------------------------------------- fused xz + LSTM recurrence (batch 63)
// 128 blocks x 512 threads, launch_bounds(512,1): VGPR budget 256 so the
// 16 float4 W_hh registers CAN stay resident; empty-asm pins make them
// un-rematerializable (r4 failure mode: compiler sank the 16 loads back
// into the step loop -> 131 KB/block/step L2 re-reads on the serial chain).
#define GROWX(RR) ((long)((RR) >> 3) * HID + 8 * g + ((RR) & 7))

#define WINIT(I) { const int ch_ = ((I) + kpart) & 15; \
    w##I = *(const float4*)(W_hh + wbase + ch_ * 4); }

#define WPIN4(A,B,C,D) asm volatile("" : \
    "+v"(w##A.x), "+v"(w##A.y), "+v"(w##A.z), "+v"(w##A.w), \
    "+v"(w##B.x), "+v"(w##B.y), "+v"(w##B.z), "+v"(w##B.w), \
    "+v"(w##C.x), "+v"(w##C.y), "+v"(w##C.z), "+v"(w##C.w), \
    "+v"(w##D.x), "+v"(w##D.y), "+v"(w##D.z), "+v"(w##D.w));

#define MACS(I) { const float4 hv_ = *(const float4*)(hb + hoff + (((I) + kpart) & 15) * 4); \
    a0 = fmaf(w##I.x, hv_.x, a0); a1 = fmaf(w##I.y, hv_.y, a1); \
    a2 = fmaf(w##I.z, hv_.z, a2); a3 = fmaf(w##I.w, hv_.w, a3); }

__global__ __launch_bounds__(512, 1) void lstm_rec(
    const float* __restrict__ W_hh,   // [4096][1024]
    const float* __restrict__ x,      // [256][64][512]
    const float* __restrict__ W_ih,   // [4096][512]
    const float* __restrict__ b_ih,
    const float* __restrict__ b_hh,
    uint64_t* __restrict__ h_all)     // [256][256] u64 (= [256][1024] bf16)
{
    __shared__ float h_lds[2][HID];            //  8 KB
    __shared__ float xz_lds[32][T_STEPS + 1];  // 32.9 KB
    __shared__ float z_lds[32];
    extern __shared__ float dyn_pad[];         // +41 KB at launch -> 1 block/CU

    const int g   = blockIdx.x;   // 0..127
    const int tid = threadIdx.x;

    // W-slice coords (needed before prologue: loads issue first)
    const int kpart = tid & 15;
    const int row   = tid >> 4;          // 0..31: gate = row>>3, ju = row&7
    const long grow  = GROWX(row);
    const long wbase = grow * HID + kpart * 64;
    const int  hoff  = kpart * 64;

    // ---------------- issue W_hh register loads FIRST (latency hides under prologue)
    float4 w0, w1, w2, w3, w4, w5, w6, w7, w8, w9, w10, w11, w12, w13, w14, w15;
    WINIT(0)  WINIT(1)  WINIT(2)  WINIT(3)
    WINIT(4)  WINIT(5)  WINIT(6)  WINIT(7)
    WINIT(8)  WINIT(9)  WINIT(10) WINIT(11)
    WINIT(12) WINIT(13) WINIT(14) WINIT(15)

    // ---------------- prologue: xz rows for this block (into LDS)
    {
        const int wv = tid >> 6;        // row-group: rows 4wv..4wv+3
        const int ln = tid & 63;        // k-part: x cols [8ln, 8ln+8)
        const int rr0 = 4 * wv;
        const long gr0 = GROWX(rr0), gr1 = GROWX(rr0 + 1),
                   gr2 = GROWX(rr0 + 2), gr3 = GROWX(rr0 + 3);
        const float4 p0a = *(const float4*)(W_ih + gr0 * IN_DIM + 8 * ln);
        const float4 p0b = *(const float4*)(W_ih + gr0 * IN_DIM + 8 * ln + 4);
        const float4 p1a = *(const float4*)(W_ih + gr1 * IN_DIM + 8 * ln);
        const float4 p1b = *(const float4*)(W_ih + gr1 * IN_DIM + 8 * ln + 4);
        const float4 p2a = *(const float4*)(W_ih + gr2 * IN_DIM + 8 * ln);
        const float4 p2b = *(const float4*)(W_ih + gr2 * IN_DIM + 8 * ln + 4);
        const float4 p3a = *(const float4*)(W_ih + gr3 * IN_DIM + 8 * ln);
        const float4 p3b = *(const float4*)(W_ih + gr3 * IN_DIM + 8 * ln + 4);
        const float bs0 = b_ih[gr0] + b_hh[gr0];
        const float bs1 = b_ih[gr1] + b_hh[gr1];
        const float bs2 = b_ih[gr2] + b_hh[gr2];
        const float bs3 = b_ih[gr3] + b_hh[gr3];
        for (int t = 0; t < T_STEPS; ++t) {
            const float* xp = x + ((long)t * BATCH + 63) * IN_DIM + 8 * ln;
            const float4 xa = *(const float4*)xp;
            const float4 xb = *(const float4*)(xp + 4);
            float s0 = xa.x*p0a.x + xa.y*p0a.y + xa.z*p0a.z + xa.w*p0a.w
                     + xb.x*p0b.x + xb.y*p0b.y + xb.z*p0b.z + xb.w*p0b.w;
            float s1 = xa.x*p1a.x + xa.y*p1a.y + xa.z*p1a.z + xa.w*p1a.w
                     + xb.x*p1b.x + xb.y*p1b.y + xb.z*p1b.z + xb.w*p1b.w;
            float s2 = xa.x*p2a.x + xa.y*p2a.y + xa.z*p2a.z + xa.w*p2a.w
                     + xb.x*p2b.x + xb.y*p2b.y + xb.z*p2b.z + xb.w*p2b.w;
            float s3 = xa.x*p3a.x + xa.y*p3a.y + xa.z*p3a.z + xa.w*p3a.w
                     + xb.x*p3b.x + xb.y*p3b.y + xb.z*p3b.z + xb.w*p3b.w;
#pragma unroll
            for (int d = 1; d < 64; d <<= 1) {
                s0 += __shfl_xor(s0, d, 64);
                s1 += __shfl_xor(s1, d, 64);
                s2 += __shfl_xor(s2, d, 64);
                s3 += __shfl_xor(s3, d, 64);
            }
            if (ln == 0) {
                xz_lds[rr0 + 0][t] = s0 + bs0;
                xz_lds[rr0 + 1][t] = s1 + bs1;
                xz_lds[rr0 + 2][t] = s2 + bs2;
                xz_lds[rr0 + 3][t] = s3 + bs3;
            }
        }
    }

    // ---------------- pin W registers: asm-defined values can't be remat'd
    WPIN4(0, 1, 2, 3)
    WPIN4(4, 5, 6, 7)
    WPIN4(8, 9, 10, 11)
    WPIN4(12, 13, 14, 15)

    // zero h_0 into buffer 0
    if (tid < 256) {
        float4 z4 = {0.f, 0.f, 0.f, 0.f};
        *(float4*)&h_lds[0][4 * tid] = z4;
    }
    __syncthreads();   // xz_lds + h_lds[0] ready

    float c_state = 0.f;                 // used by threads 0..7 (unit = tid)
    float xz_next = xz_lds[row][0];

    for (int t = 0; t < T_STEPS; ++t) {
        float* hb = h_lds[t & 1];
        if (t > 0 && tid < 128) {
            const uint64_t* src = h_all + (size_t)(t - 1) * 256 + 2 * tid;
            // 3-deep rotating pipelined poll on one 16B granule
            uint64_t v0 = poll_load(src), v1 = poll_load(src + 1);
            uint64_t a0_ = poll_load(src), a1_ = poll_load(src + 1);
            uint64_t b0_ = poll_load(src), b1_ = poll_load(src + 1);
            while (any_sent(v0) | any_sent(v1)) {
                v0 = a0_; v1 = a1_;
                a0_ = b0_; a1_ = b1_;
                b0_ = poll_load(src); b1_ = poll_load(src + 1);
            }
            float4 f0 = { bfbits2f((uint32_t)( v0        & 0xFFFFu)),
                          bfbits2f((uint32_t)((v0 >> 16) & 0xFFFFu)),
                          bfbits2f((uint32_t)((v0 >> 32) & 0xFFFFu)),
                          bfbits2f((uint32_t)((v0 >> 48) & 0xFFFFu)) };
            float4 f1 = { bfbits2f((uint32_t)( v1        & 0xFFFFu)),
                          bfbits2f((uint32_t)((v1 >> 16) & 0xFFFFu)),
                          bfbits2f((uint32_t)((v1 >> 32) & 0xFFFFu)),
                          bfbits2f((uint32_t)((v1 >> 48) & 0xFFFFu)) };
            *(float4*)&hb[8 * tid]     = f0;
            *(float4*)&hb[8 * tid + 4] = f1;
        }
        __syncthreads();   // A: h ready

        const float xz_cur = xz_next;
        const int tn = (t + 1 < T_STEPS) ? t + 1 : t;
        xz_next = xz_lds[row][tn];       // LDS broadcast prefetch

        float a0 = 0.f, a1 = 0.f, a2 = 0.f, a3 = 0.f;
        MACS(0)  MACS(1)  MACS(2)  MACS(3)
        MACS(4)  MACS(5)  MACS(6)  MACS(7)
        MACS(8)  MACS(9)  MACS(10) MACS(11)
        MACS(12) MACS(13) MACS(14) MACS(15)
        float sum = (a0 + a1) + (a2 + a3);
        sum += __shfl_xor(sum, 1, 16);
        sum += __shfl_xor(sum, 2, 16);
        sum += __shfl_xor(sum, 4, 16);
        sum += __shfl_xor(sum, 8, 16);
        if (kpart == 0) z_lds[row] = sum + xz_cur;
        __syncthreads();   // B: z ready; h_lds reads done

        // gates + state update + single 16B publish
        if (tid < 8) {
            const float zi = z_lds[tid],      zf = z_lds[8 + tid];
            const float zg = z_lds[16 + tid], zo = z_lds[24 + tid];
            const float ii = fast_sigmoid(zi);
            const float ff = fast_sigmoid(zf);
            const float gg = fast_tanh(zg);
            const float oo = fast_sigmoid(zo);
            c_state = ff * c_state + ii * gg;
            const float h = oo * fast_tanh(c_state);
            uint32_t hbv = f2bfbits(h);
            uint32_t lo  = hbv | (__shfl_down(hbv, 1, 64) << 16);  // even lanes
            uint64_t A = (uint64_t)lo | ((uint64_t)__shfl(lo, 2, 64) << 32);
            uint64_t B = (uint64_t)__shfl(lo, 4, 64)
                       | ((uint64_t)__shfl(lo, 6, 64) << 32);
            if (tid == 0) {
                uint64_t* dst = h_all + (size_t)t * 256 + 2 * g;
                __hip_atomic_store(dst,     A, __ATOMIC_RELAXED, __HIP_MEMORY_SCOPE_AGENT);
                __hip_atomic_store(dst + 1, B, __ATOMIC_RELAXED, __HIP_MEMORY_SCOPE_AGENT);
            }
        }
    }
    (void)dyn_pad;
}

// ---------------------------------------------------------------- launch
extern "C" void kernel_launch(void* const* d_in, const int* in_sizes, int n_in,
                              void* d_out, int out_size, void* d_ws, size_t ws_size,
                              hipStream_t stream) {
    const float* x    = (const float*)d_in[0];
    const float* W_ih = (const float*)d_in[1];
    const float* W_hh = (const float*)d_in[2];
    const float* b_ih = (const float*)d_in[3];
    const float* b_hh = (const float*)d_in[4];
    const float* fc_W = (const float*)d_in[5];
    const float* fc_b = (const float*)d_in[6];
    float* out = (float*)d_out;

    uint64_t* h_all = (uint64_t*)d_ws;   // [256][256] u64 = 512 KB

    // re-sentinel every replay (graph-captured)
    init_sent<<<512, 256, 0, stream>>>((uint32_t*)h_all, T_STEPS * HID / 2);

    // fused xz-GEMM + sequential recurrence; LDS pad keeps 1 block/CU
    lstm_rec<<<128, 512, 41984, stream>>>(W_hh, x, W_ih, b_ih, b_hh, h_all);

    // out[t][o] = h_all[t][:]·fc_W[o][:] + fc_b[o]
    gemm_bt<true><<<dim3(OUT_DIM / 64, T_STEPS / 64), 256, 0, stream>>>(
        (const void*)h_all, HID, fc_W, HID, fc_b, out, OUT_DIM, HID);
}